// Round 1
// baseline (3476.942 us; speedup 1.0000x reference)
//
#include <hip/hip_runtime.h>
#include <hip/hip_bf16.h>

// ---------------- problem constants ----------------
#define UNITS   400
#define BATCH   128
#define TSTEPS  1000
#define NFEAT   3
#define GATES   1600            // 4*UNITS
#define KCAP    448             // padded K (units) capacity: 13 MFMA K-tiles of 32 + pad
#define HSTR    456             // LDS row stride for H tile (bf16 elems) -> conflict-free b128
#define NGROUP  8               // batch groups (128/16)
#define CWG     20              // column-split WGs per group
#define SU      20              // units per WG
#define NCOLS   80              // 4*SU repacked cols per WG (5 MFMA N-tiles)
#define ROWS    16              // batch rows per group (one MFMA M-tile)
#define NW      5               // waves per WG
#define NTHR    320             // threads per WG

typedef __bf16 bf16x8 __attribute__((ext_vector_type(8)));
typedef float  v4f    __attribute__((ext_vector_type(4)));

__device__ __forceinline__ float sigm(float v)     { return 1.f / (1.f + __expf(-v)); }
__device__ __forceinline__ float tanhfast(float v) { return 1.f - 2.f / (1.f + __expf(2.f * v)); }

__device__ __forceinline__ unsigned short f2bf(float v) {
    __hip_bfloat16 h = __float2bfloat16(v);
    return *reinterpret_cast<unsigned short*>(&h);
}

// ---------------- init / repack kernel ----------------
// Urep: [1600][448] bf16 k-major (col = unit*4 + gate), zero-padded k>=400
// Wrep: [3][1600] f32 repacked cols; brep: [1600] f32 repacked
// Hbuf: [128][448] bf16 zeroed (h0 = 0, pad cols stay 0 forever)
// flags: 256 ints zeroed; out: [128][1000][3] init to bd[f]
__global__ void hw_init_kernel(const float* __restrict__ U, const float* __restrict__ W,
                               const float* __restrict__ b, const float* __restrict__ bd,
                               unsigned short* __restrict__ Urep, float* __restrict__ Wrep,
                               float* __restrict__ brep, unsigned short* __restrict__ Hbuf,
                               int* __restrict__ flags, float* __restrict__ out)
{
    int idx = blockIdx.x * 256 + threadIdx.x;
    if (idx < GATES * KCAP) {
        int col = idx / KCAP, k = idx - col * KCAP;
        int u = col >> 2, G = col & 3;
        float v = (k < UNITS) ? U[k * GATES + G * UNITS + u] : 0.f;
        Urep[idx] = f2bf(v);
        return;
    }
    idx -= GATES * KCAP;
    if (idx < 3 * GATES) {
        int f = idx / GATES, col = idx - f * GATES;
        int u = col >> 2, G = col & 3;
        Wrep[idx] = W[f * GATES + G * UNITS + u];
        return;
    }
    idx -= 3 * GATES;
    if (idx < GATES) {
        int u = idx >> 2, G = idx & 3;
        brep[idx] = b[G * UNITS + u];
        return;
    }
    idx -= GATES;
    if (idx < BATCH * KCAP) { Hbuf[idx] = 0; return; }
    idx -= BATCH * KCAP;
    if (idx < 256) { flags[idx] = 0; return; }
    idx -= 256;
    if (idx < BATCH * TSTEPS * NFEAT) { out[idx] = bd[idx % 3]; return; }
}

// ---------------- persistent LSTM kernel ----------------
// grid = 160 WGs: bid%8 = group (16 batch rows), bid/8 = column slice (20 units)
__global__ __launch_bounds__(NTHR) void lstm_kernel(
    const float* __restrict__ x,                    // [128][1000][3]
    const float* __restrict__ p_i, const float* __restrict__ p_f, const float* __restrict__ p_o,
    const float* __restrict__ Wd,                   // [400][3]
    const unsigned short* __restrict__ Urep,        // [1600][448] bf16
    const float* __restrict__ Wrep, const float* __restrict__ brep,
    unsigned short* __restrict__ Hbuf,              // [128][448] bf16
    int* __restrict__ flags,
    float* __restrict__ out)                        // [128][1000][3], pre-init to bd
{
    __shared__ __align__(16) unsigned short Hl[ROWS * HSTR];   // 14592 B; zb overlays
    __shared__ float Wl[3 * NCOLS];
    __shared__ float bl[NCOLS];
    __shared__ float xl[ROWS * 4];
    __shared__ float redw[NW * ROWS * 4];
    float* zb = (float*)Hl;                                    // [16][80] f32 = 5120 B

    const int tid  = threadIdx.x;
    const int lane = tid & 63, wid = tid >> 6;
    const int bid  = blockIdx.x;
    const int grp  = bid & 7;
    const int c    = bid >> 3;          // 0..19
    const int b0   = grp * ROWS;
    const int u0   = c * SU;
    const int col0 = u0 * 4;            // global repacked col base

    // ---- resident U B-fragments (13 K-tiles x 1 N-tile per wave) ----
    bf16x8 barr[13];
    {
        const int bcol = col0 + wid * 16 + (lane & 15);
        const unsigned short* up = Urep + (size_t)bcol * KCAP + ((lane >> 4) * 8);
        #pragma unroll
        for (int kt = 0; kt < 13; ++kt)
            barr[kt] = *(const bf16x8*)(up + kt * 32);
    }
    for (int i = tid; i < 3 * NCOLS; i += NTHR) {
        int f = i / NCOLS, cl = i - f * NCOLS;
        Wl[i] = Wrep[f * GATES + col0 + cl];
    }
    for (int i = tid; i < NCOLS; i += NTHR) bl[i] = brep[col0 + i];

    // ---- per-cell (row, unit) resident state ----
    const int u   = tid >> 4;           // 0..19
    const int row = tid & 15;
    const int gu  = u0 + u;
    const int gb  = b0 + row;
    const float pi = p_i[gu], pf = p_f[gu], po = p_o[gu];
    const float wd0 = Wd[gu * 3 + 0], wd1 = Wd[gu * 3 + 1], wd2 = Wd[gu * 3 + 2];
    float cst = 0.f;
    int* flagp = flags + grp * 32;

    __syncthreads();

    #pragma unroll 1
    for (int t = 0; t < TSTEPS; ++t) {
        // ---- phase A: load h(t-1) tile (coherent, bypass L1/L2) + x tile ----
        {
            const unsigned long long* src =
                (const unsigned long long*)(Hbuf + (size_t)b0 * KCAP);   // 16 rows contiguous = 1792 ull
            for (int i = tid; i < ROWS * 112; i += NTHR) {
                unsigned long long v = __hip_atomic_load(src + i, __ATOMIC_RELAXED, __HIP_MEMORY_SCOPE_AGENT);
                int r = i / 112, j = i - r * 112;
                *(unsigned long long*)((char*)Hl + r * (HSTR * 2) + j * 8) = v;
            }
            if (tid < 48) {
                int r = tid / 3, f = tid - r * 3;
                xl[r * 4 + f] = x[(size_t)(b0 + r) * (TSTEPS * NFEAT) + t * NFEAT + f];
            }
        }
        __syncthreads();

        // ---- phase B: z_slice = h @ U_slice via MFMA (B from registers) ----
        v4f acc = {0.f, 0.f, 0.f, 0.f};
        {
            const char* ap = (const char*)Hl + (lane & 15) * (HSTR * 2) + (lane >> 4) * 16;
            #pragma unroll
            for (int kt = 0; kt < 13; ++kt) {
                bf16x8 a = *(const bf16x8*)(ap + kt * 64);
                acc = __builtin_amdgcn_mfma_f32_16x16x32_bf16(a, barr[kt], acc, 0, 0, 0);
            }
        }
        __syncthreads();   // all A-frag reads done before zb overlays Hl
        {
            int zc = wid * 16 + (lane & 15);
            int zr = (lane >> 4) * 4;
            #pragma unroll
            for (int j = 0; j < 4; ++j) zb[(zr + j) * NCOLS + zc] = acc[j];
        }
        __syncthreads();

        // ---- phase C: pointwise LSTM cell (1 cell per thread) ----
        {
            float x0 = xl[row * 4 + 0], x1 = xl[row * 4 + 1], x2 = xl[row * 4 + 2];
            float z[4];
            #pragma unroll
            for (int G = 0; G < 4; ++G) {
                int cc = u * 4 + G;
                z[G] = zb[row * NCOLS + cc] + bl[cc]
                     + x0 * Wl[0 * NCOLS + cc] + x1 * Wl[1 * NCOLS + cc] + x2 * Wl[2 * NCOLS + cc];
            }
            float iv = sigm(z[0] + pi * cst);
            float fv = sigm(z[1] + pf * cst);
            float cn = fv * cst + iv * tanhfast(z[2]);
            float ov = sigm(z[3] + po * cn);
            float h  = ov * tanhfast(cn);
            cst = cn;

            // h broadcast: pack 4 units/row (this wave's 4 u's) into one 8B coherent store
            int hb = (int)f2bf(h);
            int h1 = __shfl_down(hb, 16);
            int h2 = __shfl_down(hb, 32);
            int h3 = __shfl_down(hb, 48);
            if (lane < 16) {
                unsigned int lo = (unsigned int)(hb & 0xffff) | ((unsigned int)(h1 & 0xffff) << 16);
                unsigned int hi = (unsigned int)(h2 & 0xffff) | ((unsigned int)(h3 & 0xffff) << 16);
                unsigned long long pk = (unsigned long long)lo | ((unsigned long long)hi << 32);
                __hip_atomic_store(
                    (unsigned long long*)(Hbuf + (size_t)(b0 + lane) * KCAP + u0 + wid * 4),
                    pk, __ATOMIC_RELAXED, __HIP_MEMORY_SCOPE_AGENT);
            }

            // fused output projection partials: reduce over this wave's 4 units
            float s0 = h * wd0, s1 = h * wd1, s2 = h * wd2;
            s0 += __shfl_xor(s0, 16); s0 += __shfl_xor(s0, 32);
            s1 += __shfl_xor(s1, 16); s1 += __shfl_xor(s1, 32);
            s2 += __shfl_xor(s2, 16); s2 += __shfl_xor(s2, 32);
            if (lane < 16) {
                redw[(wid * ROWS + lane) * 4 + 0] = s0;
                redw[(wid * ROWS + lane) * 4 + 1] = s1;
                redw[(wid * ROWS + lane) * 4 + 2] = s2;
            }
        }
        __syncthreads();
        if (tid < 48) {
            int f = tid >> 4, r = tid & 15;
            float s = 0.f;
            #pragma unroll
            for (int w2 = 0; w2 < NW; ++w2) s += redw[(w2 * ROWS + r) * 4 + f];
            atomicAdd(&out[(size_t)(b0 + r) * (TSTEPS * NFEAT) + t * NFEAT + f], s);
        }
        __syncthreads();   // h stores of all waves drained (vmcnt(0) before barrier)

        // ---- per-group barrier (monotonic count; relaxed atomics @ LLC) ----
        if (tid == 0) {
            __hip_atomic_fetch_add(flagp, 1, __ATOMIC_RELAXED, __HIP_MEMORY_SCOPE_AGENT);
            const int target = CWG * (t + 1);
            while (__hip_atomic_load(flagp, __ATOMIC_RELAXED, __HIP_MEMORY_SCOPE_AGENT) < target)
                __builtin_amdgcn_s_sleep(2);
        }
        __syncthreads();
    }
}

// ---------------- launch ----------------
extern "C" void kernel_launch(void* const* d_in, const int* in_sizes, int n_in,
                              void* d_out, int out_size, void* d_ws, size_t ws_size,
                              hipStream_t stream)
{
    const float* x   = (const float*)d_in[0];
    const float* W   = (const float*)d_in[1];
    const float* U   = (const float*)d_in[2];
    const float* b   = (const float*)d_in[3];
    const float* p_i = (const float*)d_in[4];
    const float* p_f = (const float*)d_in[5];
    const float* p_o = (const float*)d_in[6];
    const float* Wd  = (const float*)d_in[7];
    const float* bd  = (const float*)d_in[8];
    float* out = (float*)d_out;

    char* p = (char*)d_ws;
    unsigned short* Urep = (unsigned short*)p;  p += (size_t)GATES * KCAP * 2;   // 1,433,600
    float* Wrep = (float*)p;                    p += (size_t)3 * GATES * 4;      // 19,200
    float* brep = (float*)p;                    p += (size_t)GATES * 4;          // 6,400
    unsigned short* Hbuf = (unsigned short*)p;  p += (size_t)BATCH * KCAP * 2;   // 114,688
    int* flags = (int*)p;                       p += 256 * 4;

    const int total = GATES * KCAP + 3 * GATES + GATES + BATCH * KCAP + 256 + BATCH * TSTEPS * NFEAT;
    const int iblocks = (total + 255) / 256;
    hipLaunchKernelGGL(hw_init_kernel, dim3(iblocks), dim3(256), 0, stream,
                       U, W, b, bd, Urep, Wrep, brep, Hbuf, flags, out);

    hipLaunchKernelGGL(lstm_kernel, dim3(NGROUP * CWG), dim3(NTHR), 0, stream,
                       x, p_i, p_f, p_o, Wd, Urep, Wrep, brep, Hbuf, flags, out);
}